// Round 5
// baseline (21907.439 us; speedup 1.0000x reference)
//
#include <hip/hip_runtime.h>
#include <hip/hip_fp16.h>

#define NB 128
#define TT 256
#define MM 256
#define PP 256
#define QSCALE 2.8853900817779268f   // 2*log2(e)

typedef unsigned int uint;
typedef _Float16 hf2 __attribute__((ext_vector_type(2)));

__device__ __forceinline__ float dot2f(uint a, uint b, float c){
#if defined(__AMDGCN__) && __has_builtin(__builtin_amdgcn_fdot2)
    return __builtin_amdgcn_fdot2(__builtin_bit_cast(hf2, a), __builtin_bit_cast(hf2, b), c, false);
#else
    float2 fa = __half22float2(__builtin_bit_cast(__half2, a));
    float2 fb = __half22float2(__builtin_bit_cast(__half2, b));
    return fmaf(fa.x, fb.x, fmaf(fa.y, fb.y, c));
#endif
}

__device__ __forceinline__ float frcp(float x){ return __builtin_amdgcn_rcpf(x); }
#if defined(__AMDGCN__) && __has_builtin(__builtin_amdgcn_exp2f)
__device__ __forceinline__ float fexp2(float x){ return __builtin_amdgcn_exp2f(x); }
#else
__device__ __forceinline__ float fexp2(float x){ return exp2f(x); }
#endif
__device__ __forceinline__ float fsig(float x){ return frcp(1.f + __expf(-x)); }
__device__ __forceinline__ float ftanh(float x){ return fmaf(-2.f, frcp(1.f + __expf(2.f*x)), 1.f); }

__device__ __forceinline__ float wsum(float v){
    #pragma unroll
    for(int o=32;o;o>>=1) v += __shfl_xor(v,o);
    return v;
}
__device__ __forceinline__ float wmax(float v){
    #pragma unroll
    for(int o=32;o;o>>=1) v = fmaxf(v,__shfl_xor(v,o));
    return v;
}

// pre'[row, m] = (sum_k enc[row,k]*W1[k,m] + b1[m]) * 2log2e -> fp16
__global__ __launch_bounds__(256) void prep_pre(
    const float* __restrict__ enc, const float* __restrict__ W1,
    const float* __restrict__ b1, __half* __restrict__ pre)
{
    const int row0 = blockIdx.x * 32;
    const int col  = threadIdx.x;
    float acc[32];
    const float bias = b1[col];
    #pragma unroll
    for (int r=0;r<32;++r) acc[r]=bias;
    for (int k=0;k<256;k+=4){
        const float w0 = W1[(size_t)(k+0)*256+col];
        const float w1 = W1[(size_t)(k+1)*256+col];
        const float w2 = W1[(size_t)(k+2)*256+col];
        const float w3 = W1[(size_t)(k+3)*256+col];
        #pragma unroll
        for (int r=0;r<32;++r){
            const float4 e = *(const float4*)(enc + (size_t)(row0+r)*256 + k);
            acc[r] = fmaf(e.x,w0, fmaf(e.y,w1, fmaf(e.z,w2, fmaf(e.w,w3, acc[r]))));
        }
    }
    #pragma unroll
    for (int r=0;r<32;++r) pre[(size_t)(row0+r)*256+col] = __float2half(acc[r]*QSCALE);
}

// Wr (256,1024) f32 -> k-pair-interleaved half2: Wp[k2*1024 + j] = (Wr[2k2][j], Wr[2k2+1][j])
__global__ __launch_bounds__(256) void pack_wr(const float* __restrict__ Wr, __half2* __restrict__ Wp){
    const int idx = blockIdx.x*256 + threadIdx.x;   // 131072
    const int k2 = idx >> 10, j = idx & 1023;
    Wp[idx] = __floats2half2_rn(Wr[(size_t)(2*k2)*1024 + j], Wr[(size_t)(2*k2+1)*1024 + j]);
}
// W2 (512,256) f32 * 2log2e -> Wp[k2*256 + m]
__global__ __launch_bounds__(256) void pack_w2(const float* __restrict__ W2, __half2* __restrict__ Wp){
    const int idx = blockIdx.x*256 + threadIdx.x;   // 65536
    const int k2 = idx >> 8, m = idx & 255;
    Wp[idx] = __floats2half2_rn(W2[(size_t)(2*k2)*256 + m]*QSCALE, W2[(size_t)(2*k2+1)*256 + m]*QSCALE);
}
// edot[row] = enc[row,:] . Wd[1:257]
__global__ __launch_bounds__(256) void prep_edot(
    const float* __restrict__ enc, const float* __restrict__ Wd, float* __restrict__ edot)
{
    const int row  = blockIdx.x*4 + (threadIdx.x>>6);
    const int lane = threadIdx.x & 63;
    const float4 e = *(const float4*)(enc + (size_t)row*256 + lane*4);
    float s = e.x*Wd[1+lane*4] + e.y*Wd[2+lane*4] + e.z*Wd[3+lane*4] + e.w*Wd[4+lane*4];
    s = wsum(s);
    if (lane==0) edot[row] = s;
}

#define AGENT __HIP_MEMORY_SCOPE_AGENT
__device__ __forceinline__ uint  lda(const uint* p){ return __hip_atomic_load(p, __ATOMIC_RELAXED, AGENT); }
__device__ __forceinline__ float ldaf(const float* p){ return __hip_atomic_load(p, __ATOMIC_RELAXED, AGENT); }
__device__ __forceinline__ void  sta(uint* p, uint v){ __hip_atomic_store(p, v, __ATOMIC_RELAXED, AGENT); }
__device__ __forceinline__ void  staf(float* p, float v){ __hip_atomic_store(p, v, __ATOMIC_RELAXED, AGENT); }

// 256 blocks: even = consumer (pair b = blockIdx>>1), odd = producer.
// Producer: z_t = h_t @ Wr each step (the 512KB L2 stream), overlapped with
// consumer's attention. Handshake via agent-scope counters hcnt/zcnt.
__global__ __launch_bounds__(1024) void duo_kernel(
    const float* __restrict__ data, const float* __restrict__ enc,
    const float* __restrict__ h0, const float* __restrict__ c0,
    const float* __restrict__ Wd, const float* __restrict__ bd,
    const float* __restrict__ Wk, const float* __restrict__ bl,
    const float* __restrict__ b2, const float* __restrict__ Wv,
    const float* __restrict__ bv,
    const uint* __restrict__ Wr_u,    // [128 k2][1024 j] half2-as-uint
    const uint4* __restrict__ W2_p,   // [256 k2][64 uint4]
    const __half* __restrict__ pre,   // [B*T][256] prescaled
    const float* __restrict__ edot,   // [B*T]
    uint* hbuf, float* zbuf, uint* flags,
    float* __restrict__ out)
{
    __shared__ __half s_pre[TT*MM];      // 131072 B, swizzled
    __shared__ float s_red[4096];        // 16384 B
    __shared__ float s_h[PP], s_c[PP], s_q[MM], s_score[TT];
    __shared__ float s_r2[32];
    __shared__ __half s_Wk[1024];
    __shared__ float s_bl[1024], s_b2[MM], s_Wv[MM];
    __shared__ float s_edot[TT], s_data[TT];
    __shared__ float s_sc2[4];
    __shared__ __half s_hh[PP], s_ch[PP];

    const int tid  = threadIdx.x;
    const int lane = tid & 63;
    const int wid  = tid >> 6;
    const int b    = blockIdx.x >> 1;
    uint* hcnt = flags + 2*b;
    uint* zcnt = flags + 2*b + 1;
    uint*  hb = hbuf + b*128;
    float* zb = zbuf + (size_t)b*1024;

    if (blockIdx.x & 1){
        // ================= PRODUCER =================
        const uint* wcol = Wr_u + tid;   // j = tid
        for (int t=0; t<TT-1; ++t){
            if (tid==0){
                const uint tgt = 128u*(uint)(t+1);
                for (int sp=0; sp<(1<<23); ++sp){
                    if (__hip_atomic_load(hcnt, __ATOMIC_ACQUIRE, AGENT) >= tgt) break;
                    __builtin_amdgcn_s_sleep(4);
                }
            }
            __syncthreads();
            const uint h0v = lda(hb + lane);
            const uint h1v = lda(hb + 64 + lane);
            float a0=0.f,a1=0.f,a2=0.f,a3=0.f;
            #pragma unroll 8
            for (int k=0;k<32;++k){
                a0 = dot2f(wcol[(size_t)(k     )*1024], __shfl(h0v,k),    a0);
                a1 = dot2f(wcol[(size_t)(k + 32)*1024], __shfl(h0v,k+32), a1);
                a2 = dot2f(wcol[(size_t)(k + 64)*1024], __shfl(h1v,k),    a2);
                a3 = dot2f(wcol[(size_t)(k + 96)*1024], __shfl(h1v,k+32), a3);
            }
            staf(zb + tid, (a0+a1)+(a2+a3));
            __hip_atomic_fetch_add(zcnt, 1u, __ATOMIC_RELEASE, AGENT);
        }
        return;
    }

    // ================= CONSUMER =================
    s_Wk[tid] = __float2half(Wk[tid]);
    s_bl[tid] = bl[tid];
    if (tid < MM){
        s_b2[tid] = b2[tid]*QSCALE;
        s_Wv[tid] = Wv[tid];
        const float h0v = h0[(size_t)b*PP+tid];
        const float c0v = c0[(size_t)b*PP+tid];
        s_h[tid]  = h0v;  s_hh[tid] = __float2half(h0v);
        s_c[tid]  = c0v;  s_ch[tid] = __float2half(c0v);
        s_edot[tid] = edot[(size_t)b*TT + tid];
    }
    if (tid < TT-1) s_data[tid] = data[(size_t)b*(TT-1)+tid];
    if (tid < 8)  s_r2[20+tid] = (tid==0) ? 1.f : 0.f;   // den=1, num=0
    if (tid == 0){ s_sc2[0] = bd[0]; s_sc2[1] = bv[0]; s_sc2[2] = Wd[0]; }
    {   // stage pre[b] into LDS (swizzled)
        const uint4* g = (const uint4*)(pre + (size_t)b*TT*MM);
        const int t0 = tid >> 2, c0i = (tid & 3) * 8;
        #pragma unroll
        for (int i=0;i<8;++i){
            const int c = c0i + i;
            const uint4 v = g[t0*32 + c];
            *(uint4*)((char*)s_pre + t0*512 + ((c*16) ^ ((t0&7)<<4))) = v;
        }
    }
    __syncthreads();
    // publish h0, compute sum(Wv), wait for z_0
    if (tid < 128){
        sta(hb + tid, ((const uint*)s_hh)[tid]);
        __hip_atomic_fetch_add(hcnt, 1u, __ATOMIC_RELEASE, AGENT);
    }
    if (tid < 64){
        float wvp = s_Wv[tid]+s_Wv[tid+64]+s_Wv[tid+128]+s_Wv[tid+192];
        wvp = wsum(wvp);
        if (tid==0) s_sc2[3] = wvp;
    }
    if (tid == 0){
        for (int sp=0; sp<(1<<23); ++sp){
            if (__hip_atomic_load(zcnt, __ATOMIC_ACQUIRE, AGENT) >= 1024u) break;
            __builtin_amdgcn_s_sleep(4);
        }
    }
    __syncthreads();

    const float* erow_b = enc + (size_t)b*TT*MM;
    const int mq  = tid & 63;    // P2/epilogue: m-quad
    const int kc2 = tid >> 6;    // P2: k2-chunk 0..15; epilogue: t-chunk
    const int ttx = tid >> 2;    // P4: t index
    const int sub = tid & 3;     // P4: m sub-chunk

    for (int t=0; t<TT-1; ++t){
        // ---- P1: gates (256 threads); z from producer ----
        if (tid < PP){
            const float den = s_r2[20]+s_r2[21]+s_r2[22]+s_r2[23];
            const float num = s_r2[24]+s_r2[25]+s_r2[26]+s_r2[27];
            const float xin = num*frcp(den) + s_data[t]*s_sc2[2] + s_sc2[0];
            float z[4];
            #pragma unroll
            for (int g=0; g<4; ++g){
                const int j = tid + 256*g;
                z[g] = ldaf(zb + j) + xin*__half2float(s_Wk[j]) + s_bl[j];
            }
            const float gi = fsig(z[0]);
            const float gf = fsig(z[1]);
            const float gg = ftanh(z[2]);
            const float go = fsig(z[3]);
            const float c_new = gf*s_c[tid] + gi*gg;
            const float h_new = go*ftanh(c_new);
            s_c[tid] = c_new;
            s_h[tid] = h_new;
            s_hh[tid] = __float2half(h_new);
            s_ch[tid] = __float2half(c_new);
        }
        __syncthreads();

        // ---- publish h_{t+1} to producer ----
        if (tid < 128){
            sta(hb + tid, ((const uint*)s_hh)[tid]);
            __hip_atomic_fetch_add(hcnt, 1u, __ATOMIC_RELEASE, AGENT);
        }
        // ---- P2: q partials, [h;c] @ W2' via dot2 ----
        {
            float4 qa = make_float4(0.f,0.f,0.f,0.f);
            const uint4* wp = W2_p + (size_t)(kc2*16)*64 + mq;
            const uint*  hbp = (kc2 < 8) ? (const uint*)s_hh : (((const uint*)s_ch) - 128);
            #pragma unroll 8
            for (int i=0;i<16;++i){
                const uint4 w = wp[(size_t)i*64];
                const uint hv = hbp[kc2*16 + i];
                qa.x = dot2f(w.x,hv,qa.x); qa.y = dot2f(w.y,hv,qa.y);
                qa.z = dot2f(w.z,hv,qa.z); qa.w = dot2f(w.w,hv,qa.w);
            }
            *(float4*)&s_red[kc2*256 + mq*4] = qa;
        }
        __syncthreads();

        // ---- P3: q reduce ----
        if (tid < MM){
            float q = s_b2[tid];
            #pragma unroll
            for (int i=0;i<16;++i) q += s_red[i*256+tid];
            s_q[tid] = q;
        }
        __syncthreads();

        // ---- P4: scores via exp2 form; pre from swizzled LDS ----
        {
            float sacc = 0.f;
            const char* prow = (const char*)s_pre + ttx*512;
            const int rsw = (ttx&7)<<4;
            #pragma unroll
            for (int cch=0; cch<8; ++cch){
                const uint4 pv = *(const uint4*)(prow + (((cch*4+sub)*16) ^ rsw));
                const int m = cch*32 + sub*8;
                const float4 qv0 = *(const float4*)(&s_q[m]);
                const float4 qv1 = *(const float4*)(&s_q[m+4]);
                const float4 wv0 = *(const float4*)(&s_Wv[m]);
                const float4 wv1 = *(const float4*)(&s_Wv[m+4]);
                const float2 p0 = __half22float2(__builtin_bit_cast(__half2, pv.x));
                const float2 p1 = __half22float2(__builtin_bit_cast(__half2, pv.y));
                const float2 p2 = __half22float2(__builtin_bit_cast(__half2, pv.z));
                const float2 p3 = __half22float2(__builtin_bit_cast(__half2, pv.w));
                sacc = fmaf(wv0.x, frcp(fexp2(p0.x+qv0.x)+1.f), sacc);
                sacc = fmaf(wv0.y, frcp(fexp2(p0.y+qv0.y)+1.f), sacc);
                sacc = fmaf(wv0.z, frcp(fexp2(p1.x+qv0.z)+1.f), sacc);
                sacc = fmaf(wv0.w, frcp(fexp2(p1.y+qv0.w)+1.f), sacc);
                sacc = fmaf(wv1.x, frcp(fexp2(p2.x+qv1.x)+1.f), sacc);
                sacc = fmaf(wv1.y, frcp(fexp2(p2.y+qv1.y)+1.f), sacc);
                sacc = fmaf(wv1.z, frcp(fexp2(p3.x+qv1.z)+1.f), sacc);
                sacc = fmaf(wv1.w, frcp(fexp2(p3.y+qv1.w)+1.f), sacc);
            }
            sacc += __shfl_xor(sacc,1);
            sacc += __shfl_xor(sacc,2);
            const float sc = s_sc2[1] + s_sc2[3] - 2.f*sacc;
            if (sub==0) s_score[ttx] = sc;
            float mpart = (sub==0) ? sc : -1e30f;
            mpart = wmax(mpart);
            if (lane==0) s_r2[4+wid] = mpart;
        }
        __syncthreads();

        // ---- P5: softmax numerator + xin sums + spin for next z ----
        if (tid < TT){
            float mx = s_r2[4];
            #pragma unroll
            for (int i=1;i<16;++i) mx = fmaxf(mx, s_r2[4+i]);
            const float e = __expf(s_score[tid]-mx);
            s_score[tid] = e;
            const float pe = e * s_edot[tid];
            const float se = wsum(e);
            const float sp = wsum(pe);
            if (lane==0){ s_r2[20+wid]=se; s_r2[24+wid]=sp; }
        }
        if (tid == 0 && t < TT-2){
            const uint tgt = 1024u*(uint)(t+2);
            for (int sp=0; sp<(1<<23); ++sp){
                if (__hip_atomic_load(zcnt, __ATOMIC_ACQUIRE, AGENT) >= tgt) break;
                __builtin_amdgcn_s_sleep(4);
            }
        }
        __syncthreads();
    }

    // ---- epilogue: ctx once from final beta ----
    {
        float4 ca = make_float4(0.f,0.f,0.f,0.f);
        const float* ep = erow_b + (size_t)(kc2*16)*MM + mq*4;
        #pragma unroll 4
        for (int k=0;k<16;++k){
            const float bt = s_score[kc2*16+k];
            const float4 e = *(const float4*)(ep);
            ca.x = fmaf(bt,e.x,ca.x); ca.y = fmaf(bt,e.y,ca.y);
            ca.z = fmaf(bt,e.z,ca.z); ca.w = fmaf(bt,e.w,ca.w);
            ep += MM;
        }
        *(float4*)&s_red[kc2*256 + mq*4] = ca;
    }
    __syncthreads();
    if (tid < MM){
        const float den = s_r2[20]+s_r2[21]+s_r2[22]+s_r2[23];
        const float rd = frcp(den);
        float s = 0.f;
        #pragma unroll
        for (int i=0;i<16;++i) s += s_red[i*256+tid];
        out[(size_t)b*512 + 256 + tid] = s*rd;
        out[(size_t)b*512 + tid]       = s_h[tid];
    }
}

extern "C" void kernel_launch(void* const* d_in, const int* in_sizes, int n_in,
                              void* d_out, int out_size, void* d_ws, size_t ws_size,
                              hipStream_t stream) {
    const float* data = (const float*)d_in[0];
    const float* enc  = (const float*)d_in[1];
    const float* h0   = (const float*)d_in[2];
    const float* c0   = (const float*)d_in[3];
    const float* Wd   = (const float*)d_in[4];
    const float* bd   = (const float*)d_in[5];
    const float* Wk   = (const float*)d_in[6];
    const float* Wr   = (const float*)d_in[7];
    const float* bl   = (const float*)d_in[8];
    const float* W1   = (const float*)d_in[9];
    const float* b1   = (const float*)d_in[10];
    const float* W2   = (const float*)d_in[11];
    const float* b2   = (const float*)d_in[12];
    const float* Wv   = (const float*)d_in[13];
    const float* bv   = (const float*)d_in[14];
    float* outp = (float*)d_out;

    char* ws = (char*)d_ws;
    __half*  pre  = (__half*)(ws);                  // 16,777,216 B
    __half2* Wr_p = (__half2*)(ws + 16777216);      //    524,288 B
    __half2* W2_p = (__half2*)(ws + 17301504);      //    262,144 B
    float*   edot = (float*)(ws + 17563648);        //    131,072 B
    uint*    hbuf = (uint*)(ws + 17694720);         //     65,536 B
    float*   zbuf = (float*)(ws + 17760256);        //    524,288 B
    uint*    flags= (uint*)(ws + 18284544);         //      1,024 B

    prep_pre<<<dim3((NB*TT)/32), dim3(256), 0, stream>>>(enc, W1, b1, pre);
    pack_wr<<<dim3(512), dim3(256), 0, stream>>>(Wr, Wr_p);
    pack_w2<<<dim3(256), dim3(256), 0, stream>>>(W2, W2_p);
    prep_edot<<<dim3((NB*TT)/4), dim3(256), 0, stream>>>(enc, Wd, edot);
    hipMemsetAsync(flags, 0, 2*NB*sizeof(uint), stream);
    duo_kernel<<<dim3(2*NB), dim3(1024), 0, stream>>>(
        data, enc, h0, c0, Wd, bd, Wk, bl, b2, Wv, bv,
        (const uint*)Wr_p, (const uint4*)W2_p, pre, edot,
        hbuf, zbuf, flags, outp);
}

// Round 6
// 3374.638 us; speedup vs baseline: 6.4918x; 6.4918x over previous
//
#include <hip/hip_runtime.h>
#include <hip/hip_fp16.h>

#define NB 128
#define TT 256
#define MM 256
#define PP 256
#define QSCALE 2.8853900817779268f   // 2*log2(e)

typedef unsigned int uint;
typedef _Float16 hf2 __attribute__((ext_vector_type(2)));

__device__ __forceinline__ float dot2f(uint a, uint b, float c){
#if defined(__AMDGCN__) && __has_builtin(__builtin_amdgcn_fdot2)
    return __builtin_amdgcn_fdot2(__builtin_bit_cast(hf2, a), __builtin_bit_cast(hf2, b), c, false);
#else
    float2 fa = __half22float2(__builtin_bit_cast(__half2, a));
    float2 fb = __half22float2(__builtin_bit_cast(__half2, b));
    return fmaf(fa.x, fb.x, fmaf(fa.y, fb.y, c));
#endif
}

__device__ __forceinline__ float frcp(float x){ return __builtin_amdgcn_rcpf(x); }
#if defined(__AMDGCN__) && __has_builtin(__builtin_amdgcn_exp2f)
__device__ __forceinline__ float fexp2(float x){ return __builtin_amdgcn_exp2f(x); }
#else
__device__ __forceinline__ float fexp2(float x){ return exp2f(x); }
#endif
__device__ __forceinline__ float fsig(float x){ return frcp(1.f + __expf(-x)); }
__device__ __forceinline__ float ftanh(float x){ return fmaf(-2.f, frcp(1.f + __expf(2.f*x)), 1.f); }

__device__ __forceinline__ float wsum(float v){
    #pragma unroll
    for(int o=32;o;o>>=1) v += __shfl_xor(v,o);
    return v;
}
__device__ __forceinline__ float wmax(float v){
    #pragma unroll
    for(int o=32;o;o>>=1) v = fmaxf(v,__shfl_xor(v,o));
    return v;
}

// pre'[row, m] = (sum_k enc[row,k]*W1[k,m] + b1[m]) * 2log2e -> fp16
__global__ __launch_bounds__(256) void prep_pre(
    const float* __restrict__ enc, const float* __restrict__ W1,
    const float* __restrict__ b1, __half* __restrict__ pre)
{
    const int row0 = blockIdx.x * 32;
    const int col  = threadIdx.x;
    float acc[32];
    const float bias = b1[col];
    #pragma unroll
    for (int r=0;r<32;++r) acc[r]=bias;
    for (int k=0;k<256;k+=4){
        const float w0 = W1[(size_t)(k+0)*256+col];
        const float w1 = W1[(size_t)(k+1)*256+col];
        const float w2 = W1[(size_t)(k+2)*256+col];
        const float w3 = W1[(size_t)(k+3)*256+col];
        #pragma unroll
        for (int r=0;r<32;++r){
            const float4 e = *(const float4*)(enc + (size_t)(row0+r)*256 + k);
            acc[r] = fmaf(e.x,w0, fmaf(e.y,w1, fmaf(e.z,w2, fmaf(e.w,w3, acc[r]))));
        }
    }
    #pragma unroll
    for (int r=0;r<32;++r) pre[(size_t)(row0+r)*256+col] = __float2half(acc[r]*QSCALE);
}

// Wr (256,1024) f32 -> k-pair-interleaved half2: Wp[k2*1024 + j] = (Wr[2k2][j], Wr[2k2+1][j])
__global__ __launch_bounds__(256) void pack_wr(const float* __restrict__ Wr, __half2* __restrict__ Wp){
    const int idx = blockIdx.x*256 + threadIdx.x;   // 131072
    const int k2 = idx >> 10, j = idx & 1023;
    Wp[idx] = __floats2half2_rn(Wr[(size_t)(2*k2)*1024 + j], Wr[(size_t)(2*k2+1)*1024 + j]);
}
// W2 (512,256) f32 * 2log2e -> Wp[k2*256 + m]
__global__ __launch_bounds__(256) void pack_w2(const float* __restrict__ W2, __half2* __restrict__ Wp){
    const int idx = blockIdx.x*256 + threadIdx.x;   // 65536
    const int k2 = idx >> 8, m = idx & 255;
    Wp[idx] = __floats2half2_rn(W2[(size_t)(2*k2)*256 + m]*QSCALE, W2[(size_t)(2*k2+1)*256 + m]*QSCALE);
}
// edot[row] = enc[row,:] . Wd[1:257]
__global__ __launch_bounds__(256) void prep_edot(
    const float* __restrict__ enc, const float* __restrict__ Wd, float* __restrict__ edot)
{
    const int row  = blockIdx.x*4 + (threadIdx.x>>6);
    const int lane = threadIdx.x & 63;
    const float4 e = *(const float4*)(enc + (size_t)row*256 + lane*4);
    float s = e.x*Wd[1+lane*4] + e.y*Wd[2+lane*4] + e.z*Wd[3+lane*4] + e.w*Wd[4+lane*4];
    s = wsum(s);
    if (lane==0) edot[row] = s;
}

// One block per batch element; 1024 threads.
// Waves 8-15 (tid 512-1023): dedicated Wr-stream producer (z_{t+1} = h_t @ Wr),
// overlapped with consumer waves 0-7 doing q/scores/softmax. Lockstep barriers.
__global__ __launch_bounds__(1024) void decoder_kernel(
    const float* __restrict__ data, const float* __restrict__ enc,
    const float* __restrict__ h0, const float* __restrict__ c0,
    const float* __restrict__ Wd, const float* __restrict__ bd,
    const float* __restrict__ Wk, const float* __restrict__ bl,
    const float* __restrict__ b2, const float* __restrict__ Wv,
    const float* __restrict__ bv,
    const uint2* __restrict__ Wr2,    // [128 k2][512] uint2 (2 half2 cols)
    const uint4* __restrict__ W2_p,   // [256 k2][64 uint4]
    const __half* __restrict__ pre,   // [B*T][256] prescaled by 2log2e
    const float* __restrict__ edot,   // [B*T]
    float* __restrict__ out)
{
    __shared__ __half s_pre[TT*MM];      // 131072 B, 4-bit XOR swizzled
    __shared__ float s_red[2048];        // 8192 B
    __shared__ float s_z[1024];          // 4096 B (producer -> gates)
    __shared__ float s_h[PP], s_c[PP], s_q[MM], s_score[TT];
    __shared__ float s_r2[32];
    __shared__ __half s_Wk[1024];
    __shared__ float s_bl[1024], s_b2[MM], s_Wv[MM];
    __shared__ float s_edot[TT], s_data[TT];
    __shared__ float s_sc2[4];
    __shared__ __half s_hh[PP], s_ch[PP];

    const int tid  = threadIdx.x;
    const int lane = tid & 63;
    const int wid  = tid >> 6;
    const int b    = blockIdx.x;

    s_Wk[tid] = __float2half(Wk[tid]);
    s_bl[tid] = bl[tid];
    if (tid < MM){
        s_b2[tid] = b2[tid]*QSCALE;
        s_Wv[tid] = Wv[tid];
        const float h0v = h0[(size_t)b*PP+tid];
        const float c0v = c0[(size_t)b*PP+tid];
        s_h[tid]  = h0v;  s_hh[tid] = __float2half(h0v);
        s_c[tid]  = c0v;  s_ch[tid] = __float2half(c0v);
        s_edot[tid] = edot[(size_t)b*TT + tid];
    }
    if (tid < TT-1) s_data[tid] = data[(size_t)b*(TT-1)+tid];
    if (tid < 8)  s_r2[20+tid] = (tid==0) ? 1.f : 0.f;   // den=1, num=0 -> first xin ctx term 0
    if (tid == 0){ s_sc2[0] = bd[0]; s_sc2[1] = bv[0]; s_sc2[2] = Wd[0]; }
    __syncthreads();

    const int p = tid - 512;             // producer thread id 0..511

    if (tid < 512){
        // stage pre[b] into LDS (swizzled): row t0, 16 chunks of 16B
        const uint4* g = (const uint4*)(pre + (size_t)b*TT*MM);
        const int t0 = tid >> 1, cg = (tid & 1) * 16;
        const int rsw = (t0 & 15) << 4;
        #pragma unroll
        for (int i=0;i<16;++i){
            const int c = cg + i;
            const uint4 v = g[t0*32 + c];
            *(uint4*)((char*)s_pre + t0*512 + ((c*16) ^ rsw)) = v;
        }
        if (tid < 64){
            float wvp = s_Wv[tid]+s_Wv[tid+64]+s_Wv[tid+128]+s_Wv[tid+192];
            wvp = wsum(wvp);
            if (tid==0) s_sc2[3] = wvp;
        }
    } else {
        // initial z0 = h0 @ Wr (full 128 k2)
        const uint2* wc = Wr2 + p;
        const uint*  hu = (const uint*)s_hh;
        float a0=0.f, a1=0.f;
        #pragma unroll 8
        for (int k=0;k<128;++k){
            const uint2 w = wc[(size_t)k*512];
            const uint hv = hu[k];
            a0 = dot2f(w.x,hv,a0); a1 = dot2f(w.y,hv,a1);
        }
        *(float2*)&s_z[2*p] = make_float2(a0,a1);
    }
    __syncthreads();

    const float* erow_b = enc + (size_t)b*TT*MM;
    const int mq  = tid & 63;    // P2/epilogue: m-quad
    const int kc2 = tid >> 6;    // P2: k2-chunk 0..7 (tid<512); epilogue: t-chunk
    const int ttx = tid >> 1;    // P4: t row (tid<512)
    const int sub = tid & 1;     // P4: m half

    for (int t=0; t<TT-1; ++t){
        float a0=0.f, a1=0.f;    // producer z accumulators (live across barriers)

        // ---- P1: gates (threads 0-255); z from s_z ----
        if (tid < PP){
            const float den = s_r2[20]+s_r2[21]+s_r2[22]+s_r2[23];
            const float num = s_r2[24]+s_r2[25]+s_r2[26]+s_r2[27];
            const float xin = num*frcp(den) + s_data[t]*s_sc2[2] + s_sc2[0];
            float z[4];
            #pragma unroll
            for (int g=0; g<4; ++g){
                const int j = tid + 256*g;
                z[g] = s_z[j] + xin*__half2float(s_Wk[j]) + s_bl[j];
            }
            const float gi = fsig(z[0]);
            const float gf = fsig(z[1]);
            const float gg = ftanh(z[2]);
            const float go = fsig(z[3]);
            const float c_new = gf*s_c[tid] + gi*gg;
            const float h_new = go*ftanh(c_new);
            s_c[tid] = c_new;
            s_h[tid] = h_new;
            s_hh[tid] = __float2half(h_new);
            s_ch[tid] = __float2half(c_new);
        }
        __syncthreads();

        // ---- R2: consumers: q partials ([h;c] @ W2'); producers: Wr chunk k2 0..31 ----
        if (tid < 512){
            float4 qa = make_float4(0.f,0.f,0.f,0.f);
            const uint4* wp = W2_p + (size_t)(kc2*32)*64 + mq;
            const uint*  hbp = (kc2 < 4) ? (const uint*)s_hh : (((const uint*)s_ch) - 128);
            #pragma unroll 8
            for (int i=0;i<32;++i){
                const uint4 w = wp[(size_t)i*64];
                const uint hv = hbp[kc2*32 + i];
                qa.x = dot2f(w.x,hv,qa.x); qa.y = dot2f(w.y,hv,qa.y);
                qa.z = dot2f(w.z,hv,qa.z); qa.w = dot2f(w.w,hv,qa.w);
            }
            *(float4*)&s_red[kc2*256 + mq*4] = qa;
        } else {
            const uint2* wc = Wr2 + p;
            const uint*  hu = (const uint*)s_hh;
            #pragma unroll 8
            for (int k=0;k<32;++k){
                const uint2 w = wc[(size_t)k*512];
                const uint hv = hu[k];
                a0 = dot2f(w.x,hv,a0); a1 = dot2f(w.y,hv,a1);
            }
        }
        __syncthreads();

        // ---- P3: q reduce (threads 0-255) ----
        if (tid < MM){
            float q = s_b2[tid];
            #pragma unroll
            for (int i=0;i<8;++i) q += s_red[i*256+tid];
            s_q[tid] = q;
        }
        __syncthreads();

        // ---- R4: consumers: scores (exp2 form, pre from LDS); producers: Wr k2 32..127 + write z ----
        if (tid < 512){
            float sacc = 0.f;
            const char* prow = (const char*)s_pre + ttx*512;
            const int rsw = (ttx&15)<<4;
            #pragma unroll
            for (int cch=0; cch<16; ++cch){
                const int cc = cch*2 + sub;
                const uint4 pv = *(const uint4*)(prow + ((cc*16) ^ rsw));
                const int m = cc*8;
                const float4 qv0 = *(const float4*)(&s_q[m]);
                const float4 qv1 = *(const float4*)(&s_q[m+4]);
                const float4 wv0 = *(const float4*)(&s_Wv[m]);
                const float4 wv1 = *(const float4*)(&s_Wv[m+4]);
                const float2 p0 = __half22float2(__builtin_bit_cast(__half2, pv.x));
                const float2 p1 = __half22float2(__builtin_bit_cast(__half2, pv.y));
                const float2 p2 = __half22float2(__builtin_bit_cast(__half2, pv.z));
                const float2 p3 = __half22float2(__builtin_bit_cast(__half2, pv.w));
                sacc = fmaf(wv0.x, frcp(fexp2(p0.x+qv0.x)+1.f), sacc);
                sacc = fmaf(wv0.y, frcp(fexp2(p0.y+qv0.y)+1.f), sacc);
                sacc = fmaf(wv0.z, frcp(fexp2(p1.x+qv0.z)+1.f), sacc);
                sacc = fmaf(wv0.w, frcp(fexp2(p1.y+qv0.w)+1.f), sacc);
                sacc = fmaf(wv1.x, frcp(fexp2(p2.x+qv1.x)+1.f), sacc);
                sacc = fmaf(wv1.y, frcp(fexp2(p2.y+qv1.y)+1.f), sacc);
                sacc = fmaf(wv1.z, frcp(fexp2(p3.x+qv1.z)+1.f), sacc);
                sacc = fmaf(wv1.w, frcp(fexp2(p3.y+qv1.w)+1.f), sacc);
            }
            sacc += __shfl_xor(sacc,1);
            const float sc = s_sc2[1] + s_sc2[3] - 2.f*sacc;
            if (sub==0) s_score[ttx] = sc;
            float mpart = (sub==0) ? sc : -1e30f;
            mpart = wmax(mpart);
            if (lane==0) s_r2[4+wid] = mpart;    // 8 wave maxima
        } else {
            const uint2* wc = Wr2 + p;
            const uint*  hu = (const uint*)s_hh;
            #pragma unroll 8
            for (int k=32;k<128;++k){
                const uint2 w = wc[(size_t)k*512];
                const uint hv = hu[k];
                a0 = dot2f(w.x,hv,a0); a1 = dot2f(w.y,hv,a1);
            }
            *(float2*)&s_z[2*p] = make_float2(a0,a1);
        }
        __syncthreads();

        // ---- P5: softmax numerator + xin sums (threads 0-255) ----
        if (tid < TT){
            float mx = s_r2[4];
            #pragma unroll
            for (int i=1;i<8;++i) mx = fmaxf(mx, s_r2[4+i]);
            const float e = __expf(s_score[tid]-mx);
            s_score[tid] = e;                    // kept for epilogue beta
            const float pe = e * s_edot[tid];
            const float se = wsum(e);
            const float sp = wsum(pe);
            if (lane==0){ s_r2[20+wid]=se; s_r2[24+wid]=sp; }
        }
        __syncthreads();
    }

    // ---- epilogue: ctx once from final beta (threads 0-511) ----
    if (tid < 512){
        float4 ca = make_float4(0.f,0.f,0.f,0.f);
        const float* ep = erow_b + (size_t)(kc2*32)*MM + mq*4;
        #pragma unroll 4
        for (int k=0;k<32;++k){
            const float bt = s_score[kc2*32+k];
            const float4 e = *(const float4*)(ep);
            ca.x = fmaf(bt,e.x,ca.x); ca.y = fmaf(bt,e.y,ca.y);
            ca.z = fmaf(bt,e.z,ca.z); ca.w = fmaf(bt,e.w,ca.w);
            ep += MM;
        }
        *(float4*)&s_red[kc2*256 + mq*4] = ca;
    }
    __syncthreads();
    if (tid < MM){
        const float den = s_r2[20]+s_r2[21]+s_r2[22]+s_r2[23];
        const float rd = frcp(den);
        float s = 0.f;
        #pragma unroll
        for (int i=0;i<8;++i) s += s_red[i*256+tid];
        out[(size_t)b*512 + 256 + tid] = s*rd;
        out[(size_t)b*512 + tid]       = s_h[tid];
    }
}

extern "C" void kernel_launch(void* const* d_in, const int* in_sizes, int n_in,
                              void* d_out, int out_size, void* d_ws, size_t ws_size,
                              hipStream_t stream) {
    const float* data = (const float*)d_in[0];
    const float* enc  = (const float*)d_in[1];
    const float* h0   = (const float*)d_in[2];
    const float* c0   = (const float*)d_in[3];
    const float* Wd   = (const float*)d_in[4];
    const float* bd   = (const float*)d_in[5];
    const float* Wk   = (const float*)d_in[6];
    const float* Wr   = (const float*)d_in[7];
    const float* bl   = (const float*)d_in[8];
    const float* W1   = (const float*)d_in[9];
    const float* b1   = (const float*)d_in[10];
    const float* W2   = (const float*)d_in[11];
    const float* b2   = (const float*)d_in[12];
    const float* Wv   = (const float*)d_in[13];
    const float* bv   = (const float*)d_in[14];
    float* outp = (float*)d_out;

    char* ws = (char*)d_ws;
    __half*  pre  = (__half*)(ws);                  // 16,777,216 B
    __half2* Wr_p = (__half2*)(ws + 16777216);      //    524,288 B
    __half2* W2_p = (__half2*)(ws + 17301504);      //    262,144 B
    float*   edot = (float*)(ws + 17563648);        //    131,072 B

    prep_pre<<<dim3((NB*TT)/32), dim3(256), 0, stream>>>(enc, W1, b1, pre);
    pack_wr<<<dim3(512), dim3(256), 0, stream>>>(Wr, Wr_p);
    pack_w2<<<dim3(256), dim3(256), 0, stream>>>(W2, W2_p);
    prep_edot<<<dim3((NB*TT)/4), dim3(256), 0, stream>>>(enc, Wd, edot);
    decoder_kernel<<<dim3(NB), dim3(1024), 0, stream>>>(
        data, enc, h0, c0, Wd, bd, Wk, bl, b2, Wv, bv,
        (const uint2*)Wr_p, (const uint4*)W2_p, pre, edot, outp);
}